// Round 7
// baseline (182.695 us; speedup 1.0000x reference)
//
#include <hip/hip_runtime.h>
#include <math.h>

#define BATCH 8192
#define NU 512      // NUM_UNITS
#define NIN 256     // NUM_IN

typedef __attribute__((ext_vector_type(8))) __bf16 bf16x8;
typedef __attribute__((ext_vector_type(4))) float f32x4;

__device__ __forceinline__ float2 cmul(float2 a, float2 b){
    return make_float2(a.x*b.x - a.y*b.y, a.x*b.y + a.y*b.x);
}
__device__ __forceinline__ float2 cadd(float2 a, float2 b){ return make_float2(a.x+b.x, a.y+b.y); }
__device__ __forceinline__ float2 csub(float2 a, float2 b){ return make_float2(a.x-b.x, a.y-b.y); }

// cis(sign * 2*pi*idx/512); idx in [0,256)
template<bool INV>
__device__ __forceinline__ float2 twid512(int idx){
    float ang = 0.012271846303085129f * (float)idx;   // 2*pi/512
    float sn, cs; __sincosf(INV ? ang : -ang, &sn, &cs);
    return make_float2(cs, sn);
}

// pack two f32 -> two bf16 (RNE) in one uint
__device__ __forceinline__ unsigned int pack2bf(float x, float y){
    unsigned int ux = __float_as_uint(x);
    ux = (ux + 0x7FFFu + ((ux >> 16) & 1u)) >> 16;
    unsigned int uy = __float_as_uint(y);
    uy = (uy + 0x7FFFu + ((uy >> 16) & 1u)) & 0xFFFF0000u;
    return ux | uy;
}

// ---------------- Kernel A: P = inputs @ w_ih^T via bf16 MFMA -------------
// 128x128 tile, BK=64, 256 threads (4 waves 2x2), XOR-swizzled LDS,
// LDS-staged coalesced epilogue. (unchanged from round 6)

__device__ __forceinline__ void stage_tile(const float* __restrict__ G,
                                           char* __restrict__ lds,
                                           int kb, int tid){
    const int r0 = tid >> 3;          // 0..31
    const int kc = (tid & 7) << 3;    // 0..56, 8 floats per thread
    #pragma unroll
    for (int it = 0; it < 4; ++it){
        const int row = r0 + (it << 5);
        const float* g = G + (size_t)row * NIN + kb + kc;
        float4 v0 = *(const float4*)g;
        float4 v1 = *(const float4*)(g + 4);
        int4 w;
        w.x = (int)pack2bf(v0.x, v0.y);
        w.y = (int)pack2bf(v0.z, v0.w);
        w.z = (int)pack2bf(v1.x, v1.y);
        w.w = (int)pack2bf(v1.z, v1.w);
        int off = (row << 7) + (kc << 1);   // row*128B + kc*2B
        off ^= (row & 7) << 4;              // XOR swizzle
        *(int4*)(lds + off) = w;
    }
}

__global__ __launch_bounds__(256) void gemm_bf16(const float* __restrict__ A,
                                                 const float* __restrict__ W,
                                                 float* __restrict__ P){
    __shared__ __align__(16) char smem[2 * 128*64*2];   // 32 KiB
    char* As = smem;
    char* Bs = smem + 128*64*2;
    const int tid  = threadIdx.x;
    const int lane = tid & 63, wv = tid >> 6;
    const int wm = wv >> 1, wn = wv & 1;     // 2x2 wave grid, 64x64 each
    const int bm = blockIdx.y, bn = blockIdx.x;

    const float* Ag = A + (size_t)bm * 128 * NIN;
    const float* Wg = W + (size_t)bn * 128 * NIN;

    f32x4 acc[4][4] = {};
    const int frow = lane & 15;
    const int kq   = (lane >> 4) << 4;       // byte offset of 8-bf16 k-group

    for (int kb = 0; kb < NIN; kb += 64){
        if (kb) __syncthreads();
        stage_tile(Ag, As, kb, tid);
        stage_tile(Wg, Bs, kb, tid);
        __syncthreads();
        #pragma unroll
        for (int ks = 0; ks < 2; ++ks){
            const int koff = kq + (ks << 6);
            bf16x8 a[4], b[4];
            #pragma unroll
            for (int i = 0; i < 4; ++i){
                const int ar = wm*64 + i*16 + frow;
                a[i] = *(const bf16x8*)(As + (((ar << 7) + koff) ^ ((ar & 7) << 4)));
                const int br = wn*64 + i*16 + frow;
                b[i] = *(const bf16x8*)(Bs + (((br << 7) + koff) ^ ((br & 7) << 4)));
            }
            #pragma unroll
            for (int mi = 0; mi < 4; ++mi)
                #pragma unroll
                for (int ni = 0; ni < 4; ++ni)
                    acc[mi][ni] = __builtin_amdgcn_mfma_f32_16x16x32_bf16(
                        a[mi], b[ni], acc[mi][ni], 0, 0, 0);
        }
    }

    // epilogue: stage 32-row quarters through LDS for coalesced float4 writes.
    float* stg = (float*)smem;
    const int lr4 = (lane >> 4) << 2;
    #pragma unroll
    for (int q = 0; q < 4; ++q){
        __syncthreads();            // previous users of smem done
        if (wm == (q >> 1)){
            const int miBase = (q & 1) * 2;
            #pragma unroll
            for (int mj = 0; mj < 2; ++mj)
                #pragma unroll
                for (int ni = 0; ni < 4; ++ni)
                    #pragma unroll
                    for (int r = 0; r < 4; ++r)
                        stg[(lr4 + mj*16 + r)*132 + wn*64 + ni*16 + frow]
                            = acc[miBase + mj][ni][r];
        }
        __syncthreads();
        #pragma unroll
        for (int it = 0; it < 4; ++it){
            int idx = it*256 + tid;       // 0..1023: 32 rows x 32 float4
            int r32 = idx >> 5;
            int c4  = idx & 31;
            float4 v = *(const float4*)(stg + r32*132 + c4*4);
            int grow = bm*128 + (q >> 1)*64 + (q & 1)*32 + r32;
            *(float4*)(P + (size_t)grow*1024 + bn*128 + c4*4) = v;
        }
    }
}

// ---------------- Kernel B: wave-per-row URNN pipeline --------------------
// 1 wave = 1 batch row; 512-pt FFT as 64 lanes x 8 regs.
// This round: no shared tables, no barriers; LDS = per-wave perm buffer only
// (16 KB/block -> 8 blocks/CU); launch_bounds(256,8) caps VGPR at 64.

__device__ __forceinline__ void fft_fwd(float2 z[8], int l){
    #pragma unroll
    for (int r = 0; r < 4; ++r){
        float2 w = twid512<false>(r*64 + l);
        float2 a = z[r], b = z[r+4];
        z[r]   = cadd(a, b);
        z[r+4] = cmul(w, csub(a, b));
    }
    {
        float2 w0 = twid512<false>(2*l), w1 = twid512<false>(2*(64+l));
        const int gs[4] = {0,1,4,5};
        #pragma unroll
        for (int k = 0; k < 4; ++k){
            int g = gs[k];
            float2 w = (g & 1) ? w1 : w0;
            float2 a = z[g], b = z[g+2];
            z[g]   = cadd(a, b);
            z[g+2] = cmul(w, csub(a, b));
        }
    }
    {
        float2 w = twid512<false>(4*l);
        #pragma unroll
        for (int g = 0; g < 8; g += 2){
            float2 a = z[g], b = z[g+1];
            z[g]   = cadd(a, b);
            z[g+1] = cmul(w, csub(a, b));
        }
    }
    #pragma unroll
    for (int h = 32; h >= 1; h >>= 1){
        int m = 256 / h;
        float2 w = twid512<false>(m * (l & (h-1)));
        bool low = (l & h) != 0;
        #pragma unroll
        for (int r = 0; r < 8; ++r){
            float2 p;
            p.x = __shfl_xor(z[r].x, h);
            p.y = __shfl_xor(z[r].y, h);
            z[r] = low ? cmul(w, csub(p, z[r])) : cadd(z[r], p);
        }
    }
}

__device__ __forceinline__ void fft_inv(float2 z[8], int l){
    #pragma unroll
    for (int h = 1; h <= 32; h <<= 1){
        int m = 256 / h;
        float2 w = twid512<true>(m * (l & (h-1)));
        bool low = (l & h) != 0;
        #pragma unroll
        for (int r = 0; r < 8; ++r){
            float2 p;
            p.x = __shfl_xor(z[r].x, h);
            p.y = __shfl_xor(z[r].y, h);
            float2 t = cmul(w, low ? z[r] : p);
            z[r] = low ? csub(p, t) : cadd(z[r], t);
        }
    }
    {
        float2 w = twid512<true>(4*l);
        #pragma unroll
        for (int g = 0; g < 8; g += 2){
            float2 b = cmul(w, z[g+1]);
            z[g+1] = csub(z[g], b);
            z[g]   = cadd(z[g], b);
        }
    }
    {
        float2 w0 = twid512<true>(2*l), w1 = twid512<true>(2*(64+l));
        const int gs[4] = {0,1,4,5};
        #pragma unroll
        for (int k = 0; k < 4; ++k){
            int g = gs[k];
            float2 w = (g & 1) ? w1 : w0;
            float2 b = cmul(w, z[g+2]);
            z[g+2] = csub(z[g], b);
            z[g]   = cadd(z[g], b);
        }
    }
    #pragma unroll
    for (int r = 0; r < 4; ++r){
        float2 w = twid512<true>(r*64 + l);
        float2 b = cmul(w, z[r+4]);
        z[r+4] = csub(z[r], b);
        z[r]   = cadd(z[r], b);
    }
}

__device__ __forceinline__ void wave_reflect(float2 z[8], const float2 v[8]){
    float pr = 0.f, pi = 0.f, nn = 0.f;
    #pragma unroll
    for (int r = 0; r < 8; ++r){
        pr += v[r].x*z[r].x + v[r].y*z[r].y;
        pi += v[r].x*z[r].y - v[r].y*z[r].x;
        nn += v[r].x*v[r].x + v[r].y*v[r].y;
    }
    #pragma unroll
    for (int off = 32; off > 0; off >>= 1){
        pr += __shfl_xor(pr, off);
        pi += __shfl_xor(pi, off);
        nn += __shfl_xor(nn, off);
    }
    float c2 = 2.0f / nn;
    float2 cc = make_float2(c2*pr, c2*pi);
    #pragma unroll
    for (int r = 0; r < 8; ++r)
        z[r] = csub(z[r], cmul(cc, v[r]));
}

__global__ __launch_bounds__(256, 8) void urnn_wave(
        const float* __restrict__ states,
        const float* __restrict__ b_h,
        const float* __restrict__ d1_w,
        const float* __restrict__ r1_re, const float* __restrict__ r1_im,
        const int* __restrict__ perm,
        const float* __restrict__ d2_w,
        const float* __restrict__ r2_re, const float* __restrict__ r2_im,
        const float* __restrict__ d3_w,
        float* __restrict__ out /* in: inputs_mul, out: result */)
{
    __shared__ float2 zbuf[4][512];          // per-wave permutation buffer only

    const int tid = threadIdx.x;
    const int l = tid & 63, wv = tid >> 6;

    const int row = blockIdx.x * 4 + wv;
    const float* srow = states + (size_t)row * 1024;
    float* orow = out + (size_t)row * 1024;

    // preload inputs_mul early (T14-style: issue loads, consume at the end)
    float2 c[8];
    #pragma unroll
    for (int r = 0; r < 8; ++r) c[r] = ((const float2*)orow)[r*64 + l];

    // state load + diag1 (natural order: storage s = r*64+l holds element s)
    float2 z[8];
    #pragma unroll
    for (int r = 0; r < 8; ++r){
        int e = r*64 + l;
        float2 st = ((const float2*)srow)[e];
        float sn, cs; __sincosf(d1_w[e], &sn, &cs);
        z[r] = cmul(make_float2(cs, sn), st);
    }

    fft_fwd(z, l);                 // -> storage s holds X[rev(s)]

    { // reflection 1 in bit-reversed domain (elementwise => order-free);
      // v gathered per-wave at rev index (512-entry vectors, L1-resident)
        float2 v[8];
        #pragma unroll
        for (int r = 0; r < 8; ++r){
            int i = __brev((unsigned)(r*64 + l)) >> 23;   // rev9(s)
            v[r] = make_float2(r1_re[i], r1_im[i]);
        }
        wave_reflect(z, v);
    }

    // permutation + diag2, repacked to bitrev-for-DIT:
    // z'[s] = cis(d2[rev(s)]) * zstore[ rev9(perm[rev(s)]) ]
    {
        float2* zw = zbuf[wv];
        #pragma unroll
        for (int r = 0; r < 8; ++r) zw[r*64 + l] = z[r];
        // no barrier: buffer is private to this wave; compiler orders via lgkmcnt
        #pragma unroll
        for (int r = 0; r < 8; ++r){
            int s = r*64 + l;
            int i = __brev((unsigned)s) >> 23;            // rev9(s)
            int g = __brev((unsigned)perm[i]) >> 23;      // rev9(perm[i])
            float sn, cs; __sincosf(d2_w[i], &sn, &cs);
            z[r] = cmul(make_float2(cs, sn), zw[g]);
        }
    }

    fft_inv(z, l);                 // -> natural order

    { // reflection 2 in natural domain (coalesced global reads)
        float2 v[8];
        #pragma unroll
        for (int r = 0; r < 8; ++r){
            int e = r*64 + l;
            v[r] = make_float2(r2_re[e], r2_im[e]);
        }
        wave_reflect(z, v);
    }

    // diag3 * (1/512) + inputs_mul + modReLU; write concat([re, im])
    const float inv = 1.0f/512.0f;
    #pragma unroll
    for (int r = 0; r < 8; ++r){
        int e = r*64 + l;
        float sn, cs; __sincosf(d3_w[e], &sn, &cs);
        float2 zz = cmul(make_float2(cs, sn), z[r]);
        float2 pre = make_float2(c[r].x + zz.x*inv, c[r].y + zz.y*inv);
        float nrm = sqrtf(pre.x*pre.x + pre.y*pre.y);
        float sc = fmaxf(nrm + b_h[e], 0.f) / (nrm + 1e-6f);
        orow[e]       = sc*pre.x;
        orow[e + 512] = sc*pre.y;
    }
}

extern "C" void kernel_launch(void* const* d_in, const int* in_sizes, int n_in,
                              void* d_out, int out_size, void* d_ws, size_t ws_size,
                              hipStream_t stream) {
    const float* inputs = (const float*)d_in[0];
    const float* states = (const float*)d_in[1];
    const float* w_ih   = (const float*)d_in[2];
    const float* b_h    = (const float*)d_in[3];
    const float* d1_w   = (const float*)d_in[4];
    const float* r1_re  = (const float*)d_in[5];
    const float* r1_im  = (const float*)d_in[6];
    const int*   perm   = (const int*)d_in[7];
    const float* d2_w   = (const float*)d_in[8];
    const float* r2_re  = (const float*)d_in[9];
    const float* r2_im  = (const float*)d_in[10];
    const float* d3_w   = (const float*)d_in[11];
    float* out = (float*)d_out;

    dim3 gA(8, 64);   // 1024/128 cols, 8192/128 rows
    gemm_bf16<<<gA, 256, 0, stream>>>(inputs, w_ih, out);
    urnn_wave<<<BATCH/4, 256, 0, stream>>>(states, b_h, d1_w, r1_re, r1_im,
                                           perm, d2_w, r2_re, r2_im, d3_w, out);
}